// Round 12
// baseline (26.817 us; speedup 1.0000x reference)
//
#include <hip/hip_runtime.h>

typedef unsigned long long ull;

#define D_IN 512
#define NBLK 256
#define NTAIL 32
#define NPROD 8
#define SCALE 16777216.0f
#define INV_SCALE 5.9604644775390625e-08f
#define AG __HIP_MEMORY_SCOPE_AGENT

#define KEEP4(v) asm volatile("" : "+v"(v.x), "+v"(v.y), "+v"(v.z), "+v"(v.w))

// ws byte layout:
//   t_fixed @ 0      : ull[512][8] (32 KB) fixed-point t, TRANSPOSED   [zeroed]
//   r_fixed @ 32768  : ull[512]    (4 KB)  fixed-point r               [zeroed]
//   cnts    @ 36864  : ull[8]      (t_cnt, r_cnt)                      [zeroed]
//   rflag   @ 36928  : ull[32*8]   r-replica flags, 64B apart          [zeroed]
//   wvdone  @ 38976  : ull[32*8]   wv done slots [rep][prod]       [NOT zeroed:
//                       producers store literal 1; poison != 1 is "not done";
//                       zero range above is completed by each producer BEFORE
//                       it sets its slots -> counters safe by the wv gate]
//   rrep    @ 41024  : float[32][512] (64 KB) r replicas      [fresh-written]
//   wvrep   @ 106560 : float[32][512] (64 KB) wv replicas     [fresh-written]
#define WS_TFX    0
#define WS_RFX    32768
#define WS_CNT    36864
#define WS_RFLAG  36928
#define WS_WVDONE 38976
#define WS_RREP   41024
#define WS_WVREP  106560
#define N_ZERO    4872   // ulls: t_fixed 4096 + r_fixed 512 + cnts 8 + rflag 256

__device__ __forceinline__ void fstore_cg(float* p, float v) {
    __hip_atomic_store((unsigned*)p, __builtin_bit_cast(unsigned, v),
                       __ATOMIC_RELAXED, AG);
}
__device__ __forceinline__ ull uload_cg(const ull* p) {
    return __hip_atomic_load(p, __ATOMIC_RELAXED, AG);
}
__device__ __forceinline__ void ustore_cg(ull* p, ull v) {
    __hip_atomic_store(p, v, __ATOMIC_RELAXED, AG);
}
// 16B load forced to the coherence point (sc0+sc1 = agent-atomic-load policy).
__device__ __forceinline__ ulonglong2 load_b128_coherent(const ull* p) {
    ulonglong2 v;
    asm volatile("global_load_dwordx4 %0, %1, off sc0 sc1\n\t"
                 "s_waitcnt vmcnt(0)"
                 : "=&v"(v) : "v"(p) : "memory");
    return v;
}

// ---------------------------------------------------------------------------
// Single kernel. 256 blocks x 512 threads (1 block/CU, all co-resident).
//  P (b<8):  zero protocol state; wv columns [64b,64b+64) (column-owned, no
//            cross-producer reduce); write 32 wv replicas; set wvdone[*][b]=1.
//  A (all):  issue X->regs + W_K/W_Q prefetch FIRST, then poll wvdone[rep][0..7],
//            read wv replica (16B coherent) -> LDS.
//  B (all):  s_i dot; rank-1 t; LDS reduce; int64 t atomics (transposed).
//  C (last-32 arrivals): t fan-in via 16B coherent loads; u[8k..8k+8);
//            r slice -> r_fixed atomics; after r_cnt==32 write r replica+flag.
//  D (rest): poll own r flag; read replica; final dot from X registers.
// Deterministic: fixed-order reductions + commutative integer atomics.
// ---------------------------------------------------------------------------
__global__ __launch_bounds__(512) void k_all(
    const float* __restrict__ X,
    const float* __restrict__ W_Q,
    const float* __restrict__ W_K,
    const float* __restrict__ W_V,
    const float* __restrict__ head_w,
    const float* __restrict__ head_b,
    float* __restrict__ out,
    char* __restrict__ ws)
{
    ull*   t_fixed = (ull*)(ws + WS_TFX);     // [512][8]
    ull*   r_fixed = (ull*)(ws + WS_RFX);
    ull*   cnts    = (ull*)(ws + WS_CNT);
    ull*   t_cnt   = cnts + 0;
    ull*   r_cnt   = cnts + 1;
    ull*   rflag   = (ull*)(ws + WS_RFLAG);   // flag k at rflag[k*8]
    ull*   wvdone  = (ull*)(ws + WS_WVDONE);  // slot [rep][prod] at rep*8+prod
    float* rrep    = (float*)(ws + WS_RREP);  // [32][512]
    float* wvrep   = (float*)(ws + WS_WVREP); // [32][512]
    ull*   zbase   = (ull*)ws;                // zero range start

    const int b    = blockIdx.x;
    const int tid  = threadIdx.x;
    const int lane = tid & 63;
    const int wid  = tid >> 6;       // 0..7
    const int c0   = lane * 4;
    const int c1   = 256 + lane * 4;
    const int rep  = b & 31;

    __shared__ float lds[8][D_IN];
    __shared__ float wv_lds[D_IN];
    __shared__ float t_lds[D_IN];
    __shared__ float r_lds[D_IN];
    __shared__ float u_lds[8];
    __shared__ unsigned flag_s;

    // ---- issue this wave's 4 X rows into registers (HBM read, exactly once;
    //      latency hides under producer work / wv poll)
    float4 xa[4], xb[4];
    const int row0 = b * 32 + wid * 4;
#pragma unroll
    for (int r = 0; r < 4; ++r) {
        const float* xr = X + (size_t)(row0 + r) * D_IN;
        xa[r] = *(const float4*)(xr + c0);
        xb[r] = *(const float4*)(xr + c1);
    }
    // ---- prefetch this block's 2KB slice of W_K and W_Q into L2/L3
    {
        float pk = W_K[(size_t)b * 512 + tid];
        float pq = W_Q[(size_t)b * 512 + tid];
        asm volatile("" :: "v"(pk), "v"(pq));
    }

    // ---------------- P: producers (blocks 0..7) ---------------------------
    if (b < NPROD) {
        // zero protocol state (agent stores -> L3); share j covers 512 ulls
        for (int i = b * 512 + tid; i < N_ZERO; i += NPROD * 512)
            ustore_cg(&zbase[i], 0ull);

        // wv columns [64b, 64b+64): thread (eg=wid, cl=lane)
        float acc = 0.f;
        const int col = b * 64 + lane;
#pragma unroll 8
        for (int m = 0; m < 32; ++m) {
            const int e = m * 8 + wid;
            acc += head_w[e] * W_V[(size_t)e * D_IN + col];
        }
        lds[wid][lane] = acc;
        __syncthreads();
        if (tid < 64) {
            float s = 0.f;
#pragma unroll
            for (int w = 0; w < 8; ++w) s += lds[w][tid];
            wv_lds[tid] = s;   // stash for replica writes below
        }
        __syncthreads();
        {   // write 32 replicas of our 64 columns (each thread: 4 replicas)
            const float s = wv_lds[lane];
            for (int k = wid; k < 32; k += 8)
                fstore_cg(&wvrep[(size_t)k * D_IN + b * 64 + lane], s);
        }
        __syncthreads();   // drain zero+replica stores (waitcnt before barrier)
        if (tid < 32) ustore_cg(&wvdone[(size_t)tid * 8 + b], 1ull);
        // (no drain needed before proceeding: consumers gate on these slots)
    }

    // ---------------- A: wait for wv replica, read it -----------------------
    if (wid == 0) {
        for (;;) {
            ull v = (lane < NPROD) ? uload_cg(&wvdone[(size_t)rep * 8 + lane])
                                   : 1ull;
            if (__all((int)(v == 1ull))) break;
            __builtin_amdgcn_s_sleep(2);
        }
    }
    __syncthreads();
    if (tid < 128) {
        ulonglong2 v = load_b128_coherent(
            (const ull*)(wvrep + (size_t)rep * D_IN) + tid * 2);
        wv_lds[tid*4+0] = __builtin_bit_cast(float, (unsigned)v.x);
        wv_lds[tid*4+1] = __builtin_bit_cast(float, (unsigned)(v.x >> 32));
        wv_lds[tid*4+2] = __builtin_bit_cast(float, (unsigned)v.y);
        wv_lds[tid*4+3] = __builtin_bit_cast(float, (unsigned)(v.y >> 32));
    }
    __syncthreads();

    // ---------------- B: s_i dot + rank-1 t (X in registers) ---------------
    const float4 wv0 = *(const float4*)(wv_lds + c0);
    const float4 wv1 = *(const float4*)(wv_lds + c1);
    float4 t0 = {0.f,0.f,0.f,0.f};
    float4 t1 = {0.f,0.f,0.f,0.f};
#pragma unroll
    for (int r = 0; r < 4; ++r) {
        float p = xa[r].x*wv0.x + xa[r].y*wv0.y + xa[r].z*wv0.z + xa[r].w*wv0.w
                + xb[r].x*wv1.x + xb[r].y*wv1.y + xb[r].z*wv1.z + xb[r].w*wv1.w;
#pragma unroll
        for (int off = 32; off >= 1; off >>= 1) p += __shfl_xor(p, off, 64);
        t0.x += p*xa[r].x; t0.y += p*xa[r].y; t0.z += p*xa[r].z; t0.w += p*xa[r].w;
        t1.x += p*xb[r].x; t1.y += p*xb[r].y; t1.z += p*xb[r].z; t1.w += p*xb[r].w;
    }
    *(float4*)(&lds[wid][c0]) = t0;
    *(float4*)(&lds[wid][c1]) = t1;
    __syncthreads();
    {
        float s = 0.f;
#pragma unroll
        for (int w = 0; w < 8; ++w) s += lds[w][tid];
        const long long v = llrintf(s * SCALE);
        ull old = atomicAdd(&t_fixed[(size_t)tid * 8 + (b & 7)], (ull)v);
        unsigned keep = (unsigned)old ^ (unsigned)(old >> 32);
        asm volatile("" :: "v"(keep));   // RMW applied before barrier
    }
    __syncthreads();

    if (tid == 0) flag_s = (unsigned)atomicAdd(t_cnt, 1ull);
    __syncthreads();
    const unsigned arrival = flag_s;

    if (arrival >= (unsigned)(NBLK - NTAIL)) {
        // ---------------- C: tail work ------------------------------------
        const int k = (int)arrival - (NBLK - NTAIL);
        if (tid == 0) {
            while (uload_cg(t_cnt) < (ull)NBLK) __builtin_amdgcn_s_sleep(4);
        }
        __syncthreads();

        {   // t fan-in: 4 x 16B coherent loads of own 64B line
            long long acc = 0;
#pragma unroll
            for (int i = 0; i < 4; ++i) {
                ulonglong2 v = load_b128_coherent(&t_fixed[(size_t)tid * 8 + i * 2]);
                acc += (long long)v.x + (long long)v.y;
            }
            t_lds[tid] = (float)acc * INV_SCALE;
        }
        __syncthreads();

        {   // u[e] for e = 8k + wid (W_K L2/L3-warm from prefetch)
            const int e = 8 * k + wid;
            const float4 ta = *(const float4*)(t_lds + c0);
            const float4 tb = *(const float4*)(t_lds + c1);
            const float4 ka = *(const float4*)(W_K + (size_t)e * D_IN + c0);
            const float4 kb = *(const float4*)(W_K + (size_t)e * D_IN + c1);
            float p = ta.x*ka.x + ta.y*ka.y + ta.z*ka.z + ta.w*ka.w
                    + tb.x*kb.x + tb.y*kb.y + tb.z*kb.z + tb.w*kb.w;
#pragma unroll
            for (int off = 32; off >= 1; off >>= 1) p += __shfl_xor(p, off, 64);
            if (lane == 0) u_lds[wid] = p;
        }
        __syncthreads();

        {   // r slice -> fixed-point atomic accumulate
            float racc = 0.f;
#pragma unroll
            for (int m = 0; m < 8; ++m)
                racc += u_lds[m] * W_Q[(size_t)(8 * k + m) * D_IN + tid];
            const long long v = llrintf(racc * SCALE);
            ull old = atomicAdd(&r_fixed[tid], (ull)v);
            unsigned keep = (unsigned)old ^ (unsigned)(old >> 32);
            asm volatile("" :: "v"(keep));
        }
        __syncthreads();                 // all 512 r-RMWs applied
        if (tid == 0) atomicAdd(r_cnt, 1ull);

        if (tid == 0) {
            while (uload_cg(r_cnt) < (ull)NTAIL) __builtin_amdgcn_s_sleep(1);
        }
        __syncthreads();
        {
            ull v = uload_cg(&r_fixed[tid]);
            float f = (float)(long long)v * INV_SCALE;
            r_lds[tid] = f;
            fstore_cg(&rrep[(size_t)k * D_IN + tid], f);
        }
        __syncthreads();                 // replica stores drained
        if (tid == 0) atomicAdd(&rflag[(size_t)k * 8], 1ull);
    } else {
        // ---------------- D-wait: poll own replica flag (<=8 pollers/line) --
        if (tid == 0) {
            while (uload_cg(&rflag[(size_t)rep * 8]) == 0ull)
                __builtin_amdgcn_s_sleep(2);
        }
        __syncthreads();
        if (tid < 128) {
            ulonglong2 v = load_b128_coherent(
                (const ull*)(rrep + (size_t)rep * D_IN) + tid * 2);
            r_lds[tid*4+0] = __builtin_bit_cast(float, (unsigned)v.x);
            r_lds[tid*4+1] = __builtin_bit_cast(float, (unsigned)(v.x >> 32));
            r_lds[tid*4+2] = __builtin_bit_cast(float, (unsigned)v.y);
            r_lds[tid*4+3] = __builtin_bit_cast(float, (unsigned)(v.y >> 32));
        }
        __syncthreads();
    }

    // ---------------- final dot from the X still in registers --------------
#pragma unroll
    for (int r = 0; r < 4; ++r) { KEEP4(xa[r]); KEEP4(xb[r]); }
    const float4 r0 = *(const float4*)(r_lds + c0);
    const float4 r1 = *(const float4*)(r_lds + c1);
    const float bb  = head_b[0];

#pragma unroll
    for (int r = 0; r < 4; ++r) {
        float p = xa[r].x*r0.x + xa[r].y*r0.y + xa[r].z*r0.z + xa[r].w*r0.w
                + xb[r].x*r1.x + xb[r].y*r1.y + xb[r].z*r1.z + xb[r].w*r1.w;
#pragma unroll
        for (int off = 32; off >= 1; off >>= 1) p += __shfl_xor(p, off, 64);
        if (lane == 0) out[row0 + r] = p + bb;
    }
}

// ---------------------------------------------------------------------------
extern "C" void kernel_launch(void* const* d_in, const int* in_sizes, int n_in,
                              void* d_out, int out_size, void* d_ws, size_t ws_size,
                              hipStream_t stream) {
    const float* X      = (const float*)d_in[0];
    const float* W_Q    = (const float*)d_in[1];
    const float* W_K    = (const float*)d_in[2];
    const float* W_V    = (const float*)d_in[3];
    const float* head_w = (const float*)d_in[4];
    const float* head_b = (const float*)d_in[5];
    float* out = (float*)d_out;
    char* ws   = (char*)d_ws;

    k_all<<<NBLK, 512, 0, stream>>>(X, W_Q, W_K, W_V, head_w, head_b, out, ws);
}

// Round 13
// 24.039 us; speedup vs baseline: 1.1156x; 1.1156x over previous
//
#include <hip/hip_runtime.h>

typedef unsigned long long ull;

#define D_IN 512
#define NBLK 256
#define NTAIL 32
#define SCALE 16777216.0f
#define INV_SCALE 5.9604644775390625e-08f
#define AG __HIP_MEMORY_SCOPE_AGENT

// keep a float4 pinned in VGPRs across the protocol wait (scalar constraints;
// tuple "+v"(float4) is unsupported on gfx950 — R10 compile failure)
#define KEEP4(v) asm volatile("" : "+v"(v.x), "+v"(v.y), "+v"(v.z), "+v"(v.w))

// ws byte layout:
//   t_fixed @ 0      : ull[8*512] (32 KB) fixed-point t, 8 copies     [zeroed]
//   r_fixed @ 32768  : ull[512]   (4 KB)  fixed-point r accumulator   [zeroed]
//   cnts    @ 36864  : ull[8]     (t_cnt, r_cnt)                      [zeroed]
//   rflag   @ 36928  : ull[32*8]  flag k at +k*64B (own line each)    [zeroed]
//   rrep    @ 40960  : float[32][512] (64 KB) r replicas   [fresh-written]
//   wvp     @ 106496 : float[8*512]   (16 KB) w_v slices   [fresh-written]
#define WS_TFX   0
#define WS_RFX   32768
#define WS_CNT   36864
#define WS_RFLAG 36928
#define WS_RREP  40960
#define WS_WVP   106496
#define N_ZERO   4872    // ulls: t_fixed 4096 + r_fixed 512 + cnts 8 + rflag 256

__device__ __forceinline__ void fstore_cg(float* p, float v) {
    __hip_atomic_store((unsigned*)p, __builtin_bit_cast(unsigned, v),
                       __ATOMIC_RELAXED, AG);
}
__device__ __forceinline__ ull uload_cg(const ull* p) {
    return __hip_atomic_load(p, __ATOMIC_RELAXED, AG);
}
// 16B load forced to the coherence point (sc0+sc1 = agent-atomic-load policy).
__device__ __forceinline__ ulonglong2 load_b128_coherent(const ull* p) {
    ulonglong2 v;
    asm volatile("global_load_dwordx4 %0, %1, off sc0 sc1\n\t"
                 "s_waitcnt vmcnt(0)"
                 : "=&v"(v) : "v"(p) : "memory");
    return v;
}

// ---------------------------------------------------------------------------
// K0: wvp slices + zero protocol state (poison-proof; every call).
// ---------------------------------------------------------------------------
__global__ __launch_bounds__(512) void k_prep(const float* __restrict__ W_V,
                                              const float* __restrict__ head_w,
                                              float* __restrict__ wvp,
                                              ull* __restrict__ z) {
    const int j   = blockIdx.x;      // 0..7 -> e chunk [32j, 32j+32)
    const int tid = threadIdx.x;     // column
    float acc = 0.f;
    const int e0 = j * 32;
#pragma unroll 8
    for (int m = 0; m < 32; ++m)
        acc += head_w[e0 + m] * W_V[(size_t)(e0 + m) * D_IN + tid];
    wvp[(size_t)j * D_IN + tid] = acc;

    for (int i = j * 512 + tid; i < N_ZERO; i += 8 * 512) z[i] = 0ull;
}

// ---------------------------------------------------------------------------
// K1: single pass. 256 blocks x 512 threads (1 block/CU, all co-resident).
//  A: w_v from prep slices (plain cached); prefetch W_K/W_Q slice into L2/L3.
//  B: X -> registers (read once); s_i dot; rank-1 t; int64 t atomics (8 copies).
//  C: last-32 arrivals: t fan-in, u[8k..8k+8), r slice -> r_fixed atomics;
//     after r_cnt==32 each tail writes a FULL r replica + its own flag line.
//  D: poller b waits flag[b&31], reads replica b&31 (8-way contention only);
//     final dot from the X still in registers.
// Deterministic: fixed-order reductions + commutative integer atomics.
// ---------------------------------------------------------------------------
__global__ __launch_bounds__(512) void k_one(
    const float* __restrict__ X,
    const float* __restrict__ W_Q,
    const float* __restrict__ W_K,
    const float* __restrict__ head_b,
    float* __restrict__ out,
    char* __restrict__ ws)
{
    ull*   t_fixed = (ull*)(ws + WS_TFX);
    ull*   r_fixed = (ull*)(ws + WS_RFX);
    ull*   cnts    = (ull*)(ws + WS_CNT);
    ull*   t_cnt   = cnts + 0;
    ull*   r_cnt   = cnts + 1;
    ull*   rflag   = (ull*)(ws + WS_RFLAG);   // flag k at rflag[k*8]
    float* rrep    = (float*)(ws + WS_RREP);  // [32][512]
    const float* wvp = (const float*)(ws + WS_WVP);

    const int b    = blockIdx.x;
    const int tid  = threadIdx.x;
    const int lane = tid & 63;
    const int wid  = tid >> 6;       // 0..7
    const int c0   = lane * 4;
    const int c1   = 256 + lane * 4;

    __shared__ float lds[8][D_IN];
    __shared__ float t_lds[D_IN];
    __shared__ float r_lds[D_IN];
    __shared__ float u_lds[8];
    __shared__ unsigned flag_s;

    // ---- phase A: prefetch this block's 2KB slice of W_K and W_Q (covers
    //      both matrices exactly across 256 blocks; cacheable -> L2/L3 warm
    //      for the tail). Sink via asm to avoid DCE.
    {
        float pk = W_K[(size_t)b * 512 + tid];
        float pq = W_Q[(size_t)b * 512 + tid];
        asm volatile("" :: "v"(pk), "v"(pq));
    }
    // ---- w_v: reduce 8 prep slices with plain vectorized loads
    float4 wv0 = {0.f,0.f,0.f,0.f}, wv1 = {0.f,0.f,0.f,0.f};
#pragma unroll
    for (int j = 0; j < 8; ++j) {
        const float4 a  = *(const float4*)(wvp + (size_t)j * D_IN + c0);
        const float4 bq = *(const float4*)(wvp + (size_t)j * D_IN + c1);
        wv0.x += a.x;  wv0.y += a.y;  wv0.z += a.z;  wv0.w += a.w;
        wv1.x += bq.x; wv1.y += bq.y; wv1.z += bq.z; wv1.w += bq.w;
    }

    // ---- phase B: X rows -> registers (HBM read, exactly once)
    float4 xa[4], xb[4];
    const int row0 = b * 32 + wid * 4;
#pragma unroll
    for (int r = 0; r < 4; ++r) {
        const float* xr = X + (size_t)(row0 + r) * D_IN;
        xa[r] = *(const float4*)(xr + c0);
        xb[r] = *(const float4*)(xr + c1);
    }

    float4 t0 = {0.f,0.f,0.f,0.f};
    float4 t1 = {0.f,0.f,0.f,0.f};
#pragma unroll
    for (int r = 0; r < 4; ++r) {
        float p = xa[r].x*wv0.x + xa[r].y*wv0.y + xa[r].z*wv0.z + xa[r].w*wv0.w
                + xb[r].x*wv1.x + xb[r].y*wv1.y + xb[r].z*wv1.z + xb[r].w*wv1.w;
#pragma unroll
        for (int off = 32; off >= 1; off >>= 1) p += __shfl_xor(p, off, 64);
        t0.x += p*xa[r].x; t0.y += p*xa[r].y; t0.z += p*xa[r].z; t0.w += p*xa[r].w;
        t1.x += p*xb[r].x; t1.y += p*xb[r].y; t1.z += p*xb[r].z; t1.w += p*xb[r].w;
    }
    *(float4*)(&lds[wid][c0]) = t0;
    *(float4*)(&lds[wid][c1]) = t1;
    __syncthreads();
    {
        float s = 0.f;
#pragma unroll
        for (int w = 0; w < 8; ++w) s += lds[w][tid];
        const long long v = llrintf(s * SCALE);
        ull old = atomicAdd(&t_fixed[(size_t)(b & 7) * D_IN + tid], (ull)v);
        unsigned keep = (unsigned)old ^ (unsigned)(old >> 32);
        asm volatile("" :: "v"(keep));   // RMW applied before barrier
    }
    __syncthreads();

    if (tid == 0) flag_s = (unsigned)atomicAdd(t_cnt, 1ull);
    __syncthreads();
    const unsigned arrival = flag_s;

    if (arrival >= (unsigned)(NBLK - NTAIL)) {
        // ---- phase C (block-uniform branch): tail work
        const int k = (int)arrival - (NBLK - NTAIL);
        if (tid == 0) {
            while (uload_cg(t_cnt) < (ull)NBLK) __builtin_amdgcn_s_sleep(4);
        }
        __syncthreads();

        long long acc = 0;
#pragma unroll
        for (int j = 0; j < 8; ++j)
            acc += (long long)uload_cg(&t_fixed[(size_t)j * D_IN + tid]);
        t_lds[tid] = (float)acc * INV_SCALE;
        __syncthreads();

        {   // u[e] for e = 8k + wid (W_K row L2/L3-warm from prefetch)
            const int e = 8 * k + wid;
            const float4 ta = *(const float4*)(t_lds + c0);
            const float4 tb = *(const float4*)(t_lds + c1);
            const float4 ka = *(const float4*)(W_K + (size_t)e * D_IN + c0);
            const float4 kb = *(const float4*)(W_K + (size_t)e * D_IN + c1);
            float p = ta.x*ka.x + ta.y*ka.y + ta.z*ka.z + ta.w*ka.w
                    + tb.x*kb.x + tb.y*kb.y + tb.z*kb.z + tb.w*kb.w;
#pragma unroll
            for (int off = 32; off >= 1; off >>= 1) p += __shfl_xor(p, off, 64);
            if (lane == 0) u_lds[wid] = p;
        }
        __syncthreads();

        {   // r slice -> fixed-point atomic accumulate
            float racc = 0.f;
#pragma unroll
            for (int m = 0; m < 8; ++m)
                racc += u_lds[m] * W_Q[(size_t)(8 * k + m) * D_IN + tid];
            const long long v = llrintf(racc * SCALE);
            ull old = atomicAdd(&r_fixed[tid], (ull)v);
            unsigned keep = (unsigned)old ^ (unsigned)(old >> 32);
            asm volatile("" :: "v"(keep));
        }
        __syncthreads();                 // all 512 r-RMWs applied
        if (tid == 0) atomicAdd(r_cnt, 1ull);

        // ---- wait for full r, then broadcast a replica on own flag line
        if (tid == 0) {
            while (uload_cg(r_cnt) < (ull)NTAIL) __builtin_amdgcn_s_sleep(1);
        }
        __syncthreads();
        {
            ull v = uload_cg(&r_fixed[tid]);
            float f = (float)(long long)v * INV_SCALE;
            r_lds[tid] = f;
            fstore_cg(&rrep[(size_t)k * D_IN + tid], f);
        }
        __syncthreads();                 // replica stores drained
        if (tid == 0) atomicAdd(&rflag[(size_t)k * 8], 1ull);
    } else {
        // ---- phase D wait: poll own replica's flag (<=8 pollers per line)
        const int rep = b & 31;
        if (tid == 0) {
            while (uload_cg(&rflag[(size_t)rep * 8]) == 0ull)
                __builtin_amdgcn_s_sleep(2);
        }
        __syncthreads();
        if (tid < 128) {                 // 128 x 16B coherent loads per block
            ulonglong2 v = load_b128_coherent(
                (const ull*)(rrep + (size_t)(b & 31) * D_IN) + tid * 2);
            r_lds[tid*4+0] = __builtin_bit_cast(float, (unsigned)v.x);
            r_lds[tid*4+1] = __builtin_bit_cast(float, (unsigned)(v.x >> 32));
            r_lds[tid*4+2] = __builtin_bit_cast(float, (unsigned)v.y);
            r_lds[tid*4+3] = __builtin_bit_cast(float, (unsigned)(v.y >> 32));
        }
        __syncthreads();
    }

    // ---- final dot from the X still in registers (no memory reads)
#pragma unroll
    for (int r = 0; r < 4; ++r) { KEEP4(xa[r]); KEEP4(xb[r]); }
    const float4 r0 = *(const float4*)(r_lds + c0);
    const float4 r1 = *(const float4*)(r_lds + c1);
    const float bb  = head_b[0];

#pragma unroll
    for (int r = 0; r < 4; ++r) {
        float p = xa[r].x*r0.x + xa[r].y*r0.y + xa[r].z*r0.z + xa[r].w*r0.w
                + xb[r].x*r1.x + xb[r].y*r1.y + xb[r].z*r1.z + xb[r].w*r1.w;
#pragma unroll
        for (int off = 32; off >= 1; off >>= 1) p += __shfl_xor(p, off, 64);
        if (lane == 0) out[row0 + r] = p + bb;
    }
}

// ---------------------------------------------------------------------------
extern "C" void kernel_launch(void* const* d_in, const int* in_sizes, int n_in,
                              void* d_out, int out_size, void* d_ws, size_t ws_size,
                              hipStream_t stream) {
    const float* X      = (const float*)d_in[0];
    const float* W_Q    = (const float*)d_in[1];
    const float* W_K    = (const float*)d_in[2];
    const float* W_V    = (const float*)d_in[3];
    const float* head_w = (const float*)d_in[4];
    const float* head_b = (const float*)d_in[5];
    float* out = (float*)d_out;
    char* ws   = (char*)d_ws;

    float* wvp = (float*)(ws + WS_WVP);

    k_prep<<<8,    512, 0, stream>>>(W_V, head_w, wvp, (ull*)ws);
    k_one <<<NBLK, 512, 0, stream>>>(X, W_Q, W_K, head_b, out, ws);
}